// Round 7
// baseline (738.480 us; speedup 1.0000x reference)
//
#include <hip/hip_runtime.h>
#include <stdint.h>

// WinnerCombiner: B=64, L=4096, K=64
#define DECAY   0.6065306597126334f   // f32(e^-0.5); arithmetic bit-exact vs np ref (absmax 0.0 r1-r6)

#define B_DIM 64
#define L_DIM 4096
#define K_DIM 64

template <int CTRL>
__device__ __forceinline__ int dpp_mov(int x) {
    // old=0, row_mask=0xf, bank_mask=0xf, bound_ctrl=true (0-fill; scores >= 0 so safe for max)
    return __builtin_amdgcn_update_dpp(0, x, CTRL, 0xf, 0xf, true);
}

// 6-level DPP max; full-wave max lands in lane 63 (validated absmax 0.0, r1-r6)
__device__ __forceinline__ float wave_max_to63(float x) {
    x = fmaxf(x, __int_as_float(dpp_mov<0x111>(__float_as_int(x))));  // row_shr:1
    x = fmaxf(x, __int_as_float(dpp_mov<0x112>(__float_as_int(x))));  // row_shr:2
    x = fmaxf(x, __int_as_float(dpp_mov<0x114>(__float_as_int(x))));  // row_shr:4
    x = fmaxf(x, __int_as_float(dpp_mov<0x118>(__float_as_int(x))));  // row_shr:8
    x = fmaxf(x, __int_as_float(dpp_mov<0x142>(__float_as_int(x))));  // row_bcast:15
    x = fmaxf(x, __int_as_float(dpp_mov<0x143>(__float_as_int(x))));  // row_bcast:31
    return x;
}

// K1: 64 blocks x 64 threads, 1 wave/chain. Software-pipelined: the max-tree for
// step t+1 (function of w_{t-1} only) overlaps the scalar resolve of w_t.
//   spec0_t = fma(.5, zd_{t-1}, d2_t)  [score if lane lost t-1]  -> tree/ballot precomputed
//   spec1_t = fma(.5, za_{t-1}, d2_t)  [score if lane won  t-1]
//   M_t = max(T0_t, spec1_t[w_{t-1}]); cand = su>M0 ? wbit : (su==M0 ? b0|wbit : b0)
// Tie-break exact: spec1-spec0 ~ 0.5 never rounds equal at |score|<=3, so the
// winner lane's bit is never wrongly present in b0. (absmax 0.0 lineage r3-r6.)
__global__ __launch_bounds__(64) void k1_seq(const float* __restrict__ d2,
                                             float* __restrict__ out_idx,
                                             float* __restrict__ out_vals,
                                             float* __restrict__ out_soma) {
    const int lane = threadIdx.x;
    const int b    = blockIdx.x;
    const float* p = d2 + ((size_t)b << 18) + lane;

    float buf[16];
#pragma unroll
    for (int u = 0; u < 16; ++u) buf[u] = p[(size_t)u << 6];

    // t=0: z0=0 all lanes -> zd=za=0; spec0_0 = spec1_0 = d2_0; w_prev arbitrary.
    float zd = 0.0f, za = 0.0f;
    int   w_prev = 63;
    float spec1 = buf[0];
    unsigned M0;
    unsigned long long b0;
    {
        float tr = wave_max_to63(buf[0]);
        M0 = (unsigned)__builtin_amdgcn_readlane(__float_as_int(tr), 63);
        b0 = __ballot(__float_as_uint(buf[0]) == M0);
    }

    int   hold_i = 0;
    float hold_v = 0.0f;

    for (int g = 0; g < 256; ++g) {
#pragma unroll
        for (int u = 0; u < 16; ++u) {
            const int t    = (g << 4) + u;
            const int slot = ((g & 3) << 4) | u;       // t & 63

            // ---- (A) resolve w_t: short scalar chain ----
            unsigned su = (unsigned)__builtin_amdgcn_readlane(__float_as_int(spec1), w_prev);
            unsigned long long wbit = 1ull << w_prev;
            unsigned long long c1   = (su == M0) ? (b0 | wbit) : b0;
            unsigned long long cand = (su > M0) ? wbit : c1;
            int w = (int)__ffsll((long long)cand) - 1; // first-index argmax (jnp tiebreak)

            // ---- (B) precomp for step t+1 (depends on w_prev only, overlaps (A)) ----
            float z = (lane == w_prev) ? za : zd;      // z_t
            zd = __fmul_rn(z, DECAY);                  // z_{t+1} if lane loses t
            za = __fadd_rn(zd, 1.0f);                  // z_{t+1} if lane wins t
            float d2n = buf[(u + 1) & 15];             // d2_{t+1}
            float s0n = __builtin_fmaf(0.5f, zd, d2n); // == fadd(d2, fmul(.5,zd)) bitwise
            float s1n = __builtin_fmaf(0.5f, za, d2n);
            float trn = wave_max_to63(s0n);
            unsigned M0n = (unsigned)__builtin_amdgcn_readlane(__float_as_int(trn), 63);
            unsigned long long b0n = __ballot(__float_as_uint(s0n) == M0n);

            // ---- (C) outputs for step t (off the recurrence path) ----
            float d2v = buf[u];                        // d2_t
            unsigned vv = (unsigned)__builtin_amdgcn_readlane(__float_as_int(d2v), w);
            if (lane == slot) { hold_i = w; hold_v = __uint_as_float(vv); }

            // ---- prefetch d2_{t+16} into this slot ----
            int tn = t + 16; if (tn > L_DIM - 1) tn = L_DIM - 1;
            buf[u] = p[(size_t)tn << 6];

            // ---- commit pipeline state ----
            spec1 = s1n; M0 = M0n; b0 = b0n; w_prev = w;
        }
        if ((g & 3) == 3) {
            size_t o = ((size_t)b << 12) + ((size_t)(g >> 2) << 6) + lane;
            out_idx[o]  = (float)hold_i;
            out_vals[o] = hold_v;
            out_soma[o] = hold_v;   // w exactly one-hot in fwd float arith -> soma == vals
        }
    }
}

// K2: pure one-hot writer from idx. 1024 blocks x 256 threads; wave <-> one 64-step
// chunk. Mapping validated in r6 (absmax 0.0).
__global__ __launch_bounds__(256) void k2_par(const float* __restrict__ in_idx,
                                              float* __restrict__ out_w) {
    const int wid   = threadIdx.x >> 6;
    const int lane  = threadIdx.x & 63;
    const int chunk = (blockIdx.x << 2) | wid;         // 0..4095; row0 = chunk*64
    const size_t row0 = (size_t)chunk << 6;

    int myw = (int)in_idx[row0 + lane];                // winner of step row0+lane

    float4* pw4 = (float4*)(out_w + (row0 << 6));
    const int sub = lane >> 4;            // which of 4 rows this lane covers
    const int cb  = (lane & 15) << 2;     // channel base (4 channels per lane)
#pragma unroll
    for (int j = 0; j < 16; ++j) {
        const int r0 = j << 2;
        int wa = __builtin_amdgcn_readlane(myw, r0 + 0);
        int wb = __builtin_amdgcn_readlane(myw, r0 + 1);
        int wc = __builtin_amdgcn_readlane(myw, r0 + 2);
        int wd = __builtin_amdgcn_readlane(myw, r0 + 3);
        int t0 = (sub & 2) ? wc : wa;
        int t1 = (sub & 2) ? wd : wb;
        int wr = (sub & 1) ? t1 : t0;     // winner of row r0+sub
        float4 v;
        v.x = (cb + 0 == wr) ? 1.0f : 0.0f;
        v.y = (cb + 1 == wr) ? 1.0f : 0.0f;
        v.z = (cb + 2 == wr) ? 1.0f : 0.0f;
        v.w = (cb + 3 == wr) ? 1.0f : 0.0f;
        pw4[(size_t)((r0 + sub) << 4) + (lane & 15)] = v;
    }
}

extern "C" void kernel_launch(void* const* d_in, const int* in_sizes, int n_in,
                              void* d_out, int out_size, void* d_ws, size_t ws_size,
                              hipStream_t stream) {
    (void)in_sizes; (void)n_in; (void)out_size; (void)d_ws; (void)ws_size;

    const float* d2 = (const float*)d_in[0];
    float* out = (float*)d_out;

    const size_t BL = (size_t)B_DIM * L_DIM;          // 262144
    float* out_idx  = out;                            // [B, L]
    float* out_vals = out + BL;                       // [B, L]
    float* out_w    = out + 2 * BL;                   // [B, L, K]
    float* out_soma = out + 2 * BL + BL * K_DIM;      // [B, L]

    hipLaunchKernelGGL(k1_seq, dim3(B_DIM), dim3(64), 0, stream,
                       d2, out_idx, out_vals, out_soma);
    hipLaunchKernelGGL(k2_par, dim3(1024), dim3(256), 0, stream,
                       out_idx, out_w);
}